// Round 1
// baseline (865.461 us; speedup 1.0000x reference)
//
#include <hip/hip_runtime.h>

#define BATCH 256
#define NN 128
#define KK 32
#define NL 8

// ---------------- workspace layout (in floats) ----------------
constexpr size_t OFF_BBSUM = 0;              // 256*128*128 = 4194304
constexpr size_t OFF_G     = 4194304;        // 4194304
constexpr size_t OFF_C     = 8388608;        // 32768
constexpr size_t OFF_BZ    = 8421376;        // 32768
constexpr size_t OFF_OUT   = 8454144;        // 32768
constexpr size_t OFF_XE    = 8486912;        // 32768
constexpr size_t OFF_SSUM  = 8519680;        // 8*128 = 1024
constexpr size_t OFF_SSQ   = 8520704;        // 1024
constexpr size_t OFF_QUAD  = 8521728;        // 8
constexpr size_t OFF_LIN   = 8521736;        // 8
constexpr size_t OFF_Z2    = 8521744;        // 1
constexpr size_t ZERO_START = OFF_XE;
constexpr size_t ZERO_COUNT = 32768 + 1024 + 1024 + 8 + 8 + 1;  // 34833
// total ws: ~34.1 MB

// ---------------- zero accumulators + initial x_est ----------------
__global__ __launch_bounds__(256) void zero_kernel(float* __restrict__ p, int n) {
    int i = blockIdx.x * 256 + threadIdx.x;
    if (i < n) p[i] = 0.0f;
}

// ---------------- BB_sum[b,n,m] = sum_k BB[b,n,m,k] ----------------
__global__ __launch_bounds__(256) void reduce_bb(const float* __restrict__ BB,
                                                 float* __restrict__ BBsum) {
    size_t o = (size_t)blockIdx.x * 256 + threadIdx.x;   // 4,194,304 outputs
    const float4* p = reinterpret_cast<const float4*>(BB + o * 32);
    float s = 0.f;
#pragma unroll
    for (int i = 0; i < 8; ++i) {
        float4 v = p[i];
        s += v.x + v.y + v.z + v.w;
    }
    BBsum[o] = s;
}

// ---------------- Bz_sum[b,n] = sum_k zB[b,n,k] ----------------
__global__ __launch_bounds__(256) void reduce_zb(const float* __restrict__ zB,
                                                 float* __restrict__ Bz) {
    size_t o = (size_t)blockIdx.x * 256 + threadIdx.x;   // 32768 outputs
    const float4* p = reinterpret_cast<const float4*>(zB + o * 32);
    float s = 0.f;
#pragma unroll
    for (int i = 0; i < 8; ++i) {
        float4 v = p[i];
        s += v.x + v.y + v.z + v.w;
    }
    Bz[o] = s;
}

// ---------------- Z2 = sum z^2 ----------------
__global__ __launch_bounds__(256) void z2_kernel(const float* __restrict__ z,
                                                 float* __restrict__ Z2) {
    size_t idx = (size_t)blockIdx.x * 256 + threadIdx.x;  // 262144 float4s
    float4 v = reinterpret_cast<const float4*>(z)[idx];
    float s = v.x * v.x + v.y * v.y + v.z * v.z + v.w * v.w;
#pragma unroll
    for (int off = 32; off; off >>= 1) s += __shfl_down(s, off);
    if ((threadIdx.x & 63) == 0) atomicAdd(Z2, s);
}

// ---------------- Gram: G_b = B_b B_b^T, c_b = B_b z_b ----------------
// B_b: [128 rows x 4096 cols] row-contiguous. One block per batch, 256 threads,
// 8x8 register tile per thread, 64-col LDS chunks, register double-buffered loads.
__global__ __launch_bounds__(256) void gram_kernel(const float* __restrict__ Bmat,
                                                   const float* __restrict__ z,
                                                   float* __restrict__ G,
                                                   float* __restrict__ c) {
    const int b = blockIdx.x;
    const int t = threadIdx.x;
    const float* Bb = Bmat + (size_t)b * (128 * 4096);
    const float* zb = z + (size_t)b * 4096;

    __shared__ float As[64][132];   // [col-in-chunk][row], pad 132 for bank spread
    __shared__ float zs[64];
    __shared__ float cred[256];

    const int ty = t >> 4;    // 0..15 -> rows 8*ty..8*ty+7
    const int tx = t & 15;    // 0..15 -> cols 8*tx..8*tx+7

    float acc[8][8];
#pragma unroll
    for (int i = 0; i < 8; ++i)
#pragma unroll
        for (int j = 0; j < 8; ++j) acc[i][j] = 0.f;

    float cpart = 0.f;
    const int rr = t & 127;
    const int hh = t >> 7;

    // prefetch chunk 0
    float4 pre[8];
#pragma unroll
    for (int i = 0; i < 8; ++i) {
        int f = t + 256 * i;
        int r = f >> 4, c4 = f & 15;
        pre[i] = *reinterpret_cast<const float4*>(Bb + (size_t)r * 4096 + c4 * 4);
    }
    float zpre = (t < 64) ? zb[t] : 0.f;

    for (int ch = 0; ch < 64; ++ch) {
        // stage registers -> LDS (transposed)
#pragma unroll
        for (int i = 0; i < 8; ++i) {
            int f = t + 256 * i;
            int r = f >> 4, c4 = f & 15;
            As[c4 * 4 + 0][r] = pre[i].x;
            As[c4 * 4 + 1][r] = pre[i].y;
            As[c4 * 4 + 2][r] = pre[i].z;
            As[c4 * 4 + 3][r] = pre[i].w;
        }
        if (t < 64) zs[t] = zpre;
        __syncthreads();

        // issue next chunk's loads early (hide HBM under FMA)
        if (ch < 63) {
            const float* src = Bb + (ch + 1) * 64;
#pragma unroll
            for (int i = 0; i < 8; ++i) {
                int f = t + 256 * i;
                int r = f >> 4, c4 = f & 15;
                pre[i] = *reinterpret_cast<const float4*>(src + (size_t)r * 4096 + c4 * 4);
            }
            if (t < 64) zpre = zb[(ch + 1) * 64 + t];
        }

#pragma unroll 4
        for (int kk = 0; kk < 64; ++kk) {
            float a[8], bb[8];
            *reinterpret_cast<float4*>(&a[0]) = *reinterpret_cast<const float4*>(&As[kk][ty * 8]);
            *reinterpret_cast<float4*>(&a[4]) = *reinterpret_cast<const float4*>(&As[kk][ty * 8 + 4]);
            *reinterpret_cast<float4*>(&bb[0]) = *reinterpret_cast<const float4*>(&As[kk][tx * 8]);
            *reinterpret_cast<float4*>(&bb[4]) = *reinterpret_cast<const float4*>(&As[kk][tx * 8 + 4]);
#pragma unroll
            for (int i = 0; i < 8; ++i)
#pragma unroll
                for (int j = 0; j < 8; ++j)
                    acc[i][j] = fmaf(a[i], bb[j], acc[i][j]);
        }

        // c partial: thread handles row rr, half hh of the 64 cols
#pragma unroll
        for (int q = 0; q < 32; ++q) {
            int cc = hh * 32 + q;
            cpart = fmaf(As[cc][rr], zs[cc], cpart);
        }
        __syncthreads();
    }

    // write G_b
    float* Gb = G + (size_t)b * (128 * 128);
#pragma unroll
    for (int i = 0; i < 8; ++i) {
        int r = ty * 8 + i;
#pragma unroll
        for (int j = 0; j < 8; j += 4) {
            float4 v = make_float4(acc[i][j], acc[i][j + 1], acc[i][j + 2], acc[i][j + 3]);
            *reinterpret_cast<float4*>(Gb + r * 128 + tx * 8 + j) = v;
        }
    }

    // reduce c halves
    cred[t] = cpart;
    __syncthreads();
    if (t < 128) c[b * 128 + t] = cred[t] + cred[t + 128];
}

// ---------------- layer A: aux + affine + batch stats ----------------
__global__ __launch_bounds__(512) void layerA(const float* __restrict__ xest,
                                              const float* __restrict__ BBsum,
                                              const float* __restrict__ Bz,
                                              const float* __restrict__ w1,
                                              const float* __restrict__ b1,
                                              const float* __restrict__ w2,
                                              const float* __restrict__ b2,
                                              int l,
                                              float* __restrict__ outbuf,
                                              float* __restrict__ ssum,
                                              float* __restrict__ ssq) {
    const int b = blockIdx.x;
    const int t = threadIdx.x;
    const int m = t & 127, g = t >> 7;   // g: 0..3 (n-quarter)
    __shared__ float xs[128];
    __shared__ float part[4][128];
    if (t < 128) xs[t] = xest[b * 128 + t];
    __syncthreads();
    const float* BBb = BBsum + (size_t)b * 16384;
    float s = 0.f;
#pragma unroll 8
    for (int n = g * 32; n < g * 32 + 32; ++n)
        s = fmaf(xs[n], BBb[n * 128 + m], s);
    part[g][m] = s;
    __syncthreads();
    if (t < 128) {
        float aux = part[0][m] + part[1][m] + part[2][m] + part[3][m] - Bz[b * 128 + m];
        float xe = xs[m];
        float out = fmaf(aux, w1[l * 128 + m], b1[l * 128 + m]) +
                    fmaf(xe, w2[l * 128 + m], b2[l * 128 + m]);
        outbuf[b * 128 + m] = out;
        atomicAdd(&ssum[l * 128 + m], out);
        atomicAdd(&ssq[l * 128 + m], out * out);
    }
}

// ---------------- layer B: BN + mask + clip(2v) + loss terms ----------------
__global__ __launch_bounds__(512) void layerB(const float* __restrict__ outbuf,
                                              const float* __restrict__ ssum,
                                              const float* __restrict__ ssq,
                                              const float* __restrict__ gamma,
                                              const float* __restrict__ beta,
                                              const float* __restrict__ Mask,
                                              int l,
                                              const float* __restrict__ G,
                                              const float* __restrict__ c,
                                              float* __restrict__ xest,
                                              float* __restrict__ dout,
                                              float* __restrict__ quad,
                                              float* __restrict__ lin) {
    const int b = blockIdx.x;
    const int t = threadIdx.x;
    const int m = t & 127, g = t >> 7;
    __shared__ float xs[128];
    __shared__ float part[4][128];
    __shared__ float red[16];
    if (t < 128) {
        float mu = ssum[l * 128 + t] * (1.0f / 256.0f);
        float var = ssq[l * 128 + t] * (1.0f / 256.0f) - mu * mu;
        float inv = 1.0f / sqrtf(var + 1e-5f);
        float v = (outbuf[b * 128 + t] - mu) * inv * gamma[l * 128 + t] + beta[l * 128 + t];
        v *= Mask[b * 128 + t];
        // _piecewise_clip(v) == clamp(2v, -1, 1)
        float xe = fminf(1.0f, fmaxf(-1.0f, 2.0f * v));
        xs[t] = xe;
        xest[b * 128 + t] = xe;
        dout[b * 128 + t] = xe;   // x_est output region (last layer's value survives)
    }
    __syncthreads();
    const float* Gb = G + (size_t)b * 16384;
    float s = 0.f;
#pragma unroll 8
    for (int n = g * 32; n < g * 32 + 32; ++n)
        s = fmaf(xs[n], Gb[n * 128 + m], s);
    part[g][m] = s;
    __syncthreads();
    float vq = 0.f, vl = 0.f;
    if (t < 128) {
        float sm = part[0][m] + part[1][m] + part[2][m] + part[3][m];
        vq = xs[m] * sm;            // contributes to x^T G x
        vl = xs[m] * c[b * 128 + m];// contributes to x . c
    }
#pragma unroll
    for (int off = 32; off; off >>= 1) {
        vq += __shfl_down(vq, off);
        vl += __shfl_down(vl, off);
    }
    const int wid = t >> 6, lane = t & 63;
    if (lane == 0) { red[wid] = vq; red[8 + wid] = vl; }
    __syncthreads();
    if (t == 0) {
        float q = 0.f, L = 0.f;
#pragma unroll
        for (int w = 0; w < 8; ++w) { q += red[w]; L += red[8 + w]; }
        atomicAdd(&quad[l], q);
        atomicAdd(&lin[l], L);
    }
}

// ---------------- final: losses[l] = log(l+1) * (Z2 - 2 lin + quad)/32768 ----------------
__global__ void final_losses(const float* __restrict__ quad,
                             const float* __restrict__ lin,
                             const float* __restrict__ Z2,
                             float* __restrict__ dout) {
    int l = threadIdx.x;
    if (l < 8) {
        const float logs[8] = {0.0f,
                               0.6931471805599453f,
                               1.0986122886681098f,
                               1.3862943611198906f,
                               1.6094379124341003f,
                               1.7917594692280550f,
                               1.9459101490553132f,
                               2.0794415416798357f};
        float dis = (Z2[0] - 2.0f * lin[l] + quad[l]) * (1.0f / 32768.0f);
        dout[32768 + l] = logs[l] * dis;
    }
}

extern "C" void kernel_launch(void* const* d_in, const int* in_sizes, int n_in,
                              void* d_out, int out_size, void* d_ws, size_t ws_size,
                              hipStream_t stream) {
    (void)in_sizes; (void)n_in; (void)out_size; (void)ws_size;
    const float* BB    = (const float*)d_in[0];
    const float* zB    = (const float*)d_in[1];
    // d_in[2] = x : unused (x_est starts at zeros)
    const float* z     = (const float*)d_in[3];
    const float* Bmat  = (const float*)d_in[4];
    const float* Mask  = (const float*)d_in[5];
    const float* w1    = (const float*)d_in[6];
    const float* b1    = (const float*)d_in[7];
    const float* w2    = (const float*)d_in[8];
    const float* b2    = (const float*)d_in[9];
    const float* gamma = (const float*)d_in[10];
    const float* beta  = (const float*)d_in[11];

    float* ws  = (float*)d_ws;
    float* out = (float*)d_out;

    float* BBsum = ws + OFF_BBSUM;
    float* G     = ws + OFF_G;
    float* c     = ws + OFF_C;
    float* Bz    = ws + OFF_BZ;
    float* outb  = ws + OFF_OUT;
    float* xe    = ws + OFF_XE;
    float* ssum  = ws + OFF_SSUM;
    float* ssq   = ws + OFF_SSQ;
    float* quad  = ws + OFF_QUAD;
    float* lin   = ws + OFF_LIN;
    float* Z2    = ws + OFF_Z2;

    zero_kernel<<<(int)((ZERO_COUNT + 255) / 256), 256, 0, stream>>>(ws + ZERO_START, (int)ZERO_COUNT);
    reduce_bb<<<16384, 256, 0, stream>>>(BB, BBsum);
    reduce_zb<<<128, 256, 0, stream>>>(zB, Bz);
    z2_kernel<<<1024, 256, 0, stream>>>(z, Z2);
    gram_kernel<<<256, 256, 0, stream>>>(Bmat, z, G, c);
    for (int l = 0; l < NL; ++l) {
        layerA<<<256, 512, 0, stream>>>(xe, BBsum, Bz, w1, b1, w2, b2, l, outb, ssum, ssq);
        layerB<<<256, 512, 0, stream>>>(outb, ssum, ssq, gamma, beta, Mask, l, G, c, xe, out, quad, lin);
    }
    final_losses<<<1, 64, 0, stream>>>(quad, lin, Z2, out);
}

// Round 2
// 457.654 us; speedup vs baseline: 1.8911x; 1.8911x over previous
//
#include <hip/hip_runtime.h>

#define BATCH 256
#define NN 128
#define KK 32
#define NL 8

typedef __attribute__((ext_vector_type(8))) short bf16x8;
typedef __attribute__((ext_vector_type(16))) float f32x16;

// ---------------- workspace layout (in floats) ----------------
constexpr size_t OFF_BBSUM = 0;              // 256*128*128 = 4194304
constexpr size_t OFF_G     = 4194304;        // 4194304
constexpr size_t OFF_C     = 8388608;        // 32768
constexpr size_t OFF_BZ    = 8421376;        // 32768
constexpr size_t OFF_OUT   = 8454144;        // 32768
constexpr size_t OFF_XE    = 8486912;        // 32768
constexpr size_t OFF_SSUM  = 8519680;        // 8*128 = 1024
constexpr size_t OFF_SSQ   = 8520704;        // 1024
constexpr size_t OFF_QUAD  = 8521728;        // 8
constexpr size_t OFF_LIN   = 8521736;        // 8
constexpr size_t OFF_Z2    = 8521744;        // 1
constexpr size_t ZERO_START = OFF_XE;
constexpr size_t ZERO_COUNT = 32768 + 1024 + 1024 + 8 + 8 + 1;  // 34833

__device__ inline ushort f2bf(float f) {
    unsigned u = __float_as_uint(f);
    unsigned r = (u + 0x7FFFu + ((u >> 16) & 1u)) >> 16;
    return (ushort)r;
}

// ---------------- zero accumulators + initial x_est ----------------
__global__ __launch_bounds__(256) void zero_kernel(float* __restrict__ p, int n) {
    int i = blockIdx.x * 256 + threadIdx.x;
    if (i < n) p[i] = 0.0f;
}

// ---------------- BB_sum[b,n,m] = sum_k BB[b,n,m,k] ----------------
__global__ __launch_bounds__(256) void reduce_bb(const float* __restrict__ BB,
                                                 float* __restrict__ BBsum) {
    size_t o = (size_t)blockIdx.x * 256 + threadIdx.x;   // 4,194,304 outputs
    const float4* p = reinterpret_cast<const float4*>(BB + o * 32);
    float s = 0.f;
#pragma unroll
    for (int i = 0; i < 8; ++i) {
        float4 v = p[i];
        s += v.x + v.y + v.z + v.w;
    }
    BBsum[o] = s;
}

// ---------------- Bz_sum[b,n] = sum_k zB[b,n,k] ----------------
__global__ __launch_bounds__(256) void reduce_zb(const float* __restrict__ zB,
                                                 float* __restrict__ Bz) {
    size_t o = (size_t)blockIdx.x * 256 + threadIdx.x;   // 32768 outputs
    const float4* p = reinterpret_cast<const float4*>(zB + o * 32);
    float s = 0.f;
#pragma unroll
    for (int i = 0; i < 8; ++i) {
        float4 v = p[i];
        s += v.x + v.y + v.z + v.w;
    }
    Bz[o] = s;
}

// ---------------- Z2 = sum z^2 ----------------
__global__ __launch_bounds__(256) void z2_kernel(const float* __restrict__ z,
                                                 float* __restrict__ Z2) {
    size_t idx = (size_t)blockIdx.x * 256 + threadIdx.x;  // 262144 float4s
    float4 v = reinterpret_cast<const float4*>(z)[idx];
    float s = v.x * v.x + v.y * v.y + v.z * v.z + v.w * v.w;
#pragma unroll
    for (int off = 32; off; off >>= 1) s += __shfl_down(s, off);
    if ((threadIdx.x & 63) == 0) atomicAdd(Z2, s);
}

// ---------------- Gram via MFMA: G_b = B_b B_b^T (bf16), c_b = B_b z_b ----
// One block (1024 thr = 16 waves) per batch. Wave w owns output tile
// (wr=w>>2, wc=w&3) of 32x32. K staged in 64-col bf16 chunks, LDS
// [128][72] (16B row pad -> balanced banks for b64 writes & b128 reads).
// Diagonal waves additionally compute c rows via an extra MFMA whose
// B-operand has z in column 0.
#define KC 64
#define LDST 72

__global__ __launch_bounds__(1024) void gram_mfma(const float* __restrict__ Bmat,
                                                  const float* __restrict__ z,
                                                  float* __restrict__ G,
                                                  float* __restrict__ cvec) {
    const int b = blockIdx.x;
    const int t = threadIdx.x;
    const int w = t >> 6;
    const int lane = t & 63;
    const int wr = w >> 2, wc = w & 3;
    const bool diag = (wr == wc);
    const int kg = lane >> 5;        // which k-half (0: k0-7, 1: k8-15)
    const int l31 = lane & 31;

    const float* Bb = Bmat + (size_t)b * (128 * 4096);
    const float* zb = z + (size_t)b * 4096;

    __shared__ ushort As[2][128 * LDST];   // 2 x 18 KiB
    __shared__ ushort zsb[2][64];

    const int c4 = t & 15;           // float4 index within 64-col chunk
    const int r0 = t >> 4;           // 0..63 -> rows r0, r0+64

    f32x16 acc, cacc;
#pragma unroll
    for (int i = 0; i < 16; ++i) { acc[i] = 0.f; cacc[i] = 0.f; }

    const int arow = wr * 32 + l31;
    const int brow = wc * 32 + l31;
    const int foff_a = arow * LDST + kg * 8;
    const int foff_b = brow * LDST + kg * 8;

    // prefetch chunk 0
    float4 pre0 = *(const float4*)(Bb + (size_t)r0 * 4096 + c4 * 4);
    float4 pre1 = *(const float4*)(Bb + (size_t)(r0 + 64) * 4096 + c4 * 4);
    float4 zpre;
    if (t < 16) zpre = *(const float4*)(zb + t * 4);

    for (int ch = 0; ch < 64; ++ch) {
        const int cur = ch & 1;
        // stage regs -> LDS[cur] (bf16 RNE convert)
        {
            ushort4 u0 = make_ushort4(f2bf(pre0.x), f2bf(pre0.y), f2bf(pre0.z), f2bf(pre0.w));
            ushort4 u1 = make_ushort4(f2bf(pre1.x), f2bf(pre1.y), f2bf(pre1.z), f2bf(pre1.w));
            *(ushort4*)&As[cur][r0 * LDST + c4 * 4] = u0;
            *(ushort4*)&As[cur][(r0 + 64) * LDST + c4 * 4] = u1;
            if (t < 16) {
                ushort4 uz = make_ushort4(f2bf(zpre.x), f2bf(zpre.y), f2bf(zpre.z), f2bf(zpre.w));
                *(ushort4*)&zsb[cur][t * 4] = uz;
            }
        }
        __syncthreads();
        // issue next chunk's global loads (in flight under MFMA + next stage)
        if (ch < 63) {
            const float* src = Bb + (ch + 1) * KC;
            pre0 = *(const float4*)(src + (size_t)r0 * 4096 + c4 * 4);
            pre1 = *(const float4*)(src + (size_t)(r0 + 64) * 4096 + c4 * 4);
            if (t < 16) zpre = *(const float4*)(zb + (ch + 1) * KC + t * 4);
        }
        // MFMA over this chunk (KC=64 -> 4 k-steps of 16)
#pragma unroll
        for (int ks = 0; ks < 4; ++ks) {
            bf16x8 a = *(const bf16x8*)&As[cur][foff_a + ks * 16];
            bf16x8 bfr = *(const bf16x8*)&As[cur][foff_b + ks * 16];
            acc = __builtin_amdgcn_mfma_f32_32x32x16_bf16(a, bfr, acc, 0, 0, 0);
            if (diag) {
                bf16x8 zf;
#pragma unroll
                for (int i = 0; i < 8; ++i) zf[i] = 0;
                if (l31 == 0) zf = *(const bf16x8*)&zsb[cur][ks * 16 + kg * 8];
                cacc = __builtin_amdgcn_mfma_f32_32x32x16_bf16(a, zf, cacc, 0, 0, 0);
            }
        }
        // note: no second barrier needed — next iter writes LDS[cur^1],
        // whose readers finished before THIS iter's barrier.
    }

    // epilogue: C/D layout col=lane&31, row=(reg&3)+8*(reg>>2)+4*(lane>>5)
    float* Gb = G + (size_t)b * 16384;
#pragma unroll
    for (int r = 0; r < 16; ++r) {
        int row = wr * 32 + (r & 3) + 8 * (r >> 2) + 4 * kg;
        Gb[row * 128 + wc * 32 + l31] = acc[r];
    }
    if (diag && l31 == 0) {
#pragma unroll
        for (int r = 0; r < 16; ++r) {
            int row = wr * 32 + (r & 3) + 8 * (r >> 2) + 4 * kg;
            cvec[b * 128 + row] = cacc[r];
        }
    }
}

// ---------------- layer A: aux + affine + batch stats ----------------
__global__ __launch_bounds__(512) void layerA(const float* __restrict__ xest,
                                              const float* __restrict__ BBsum,
                                              const float* __restrict__ Bz,
                                              const float* __restrict__ w1,
                                              const float* __restrict__ b1,
                                              const float* __restrict__ w2,
                                              const float* __restrict__ b2,
                                              int l,
                                              float* __restrict__ outbuf,
                                              float* __restrict__ ssum,
                                              float* __restrict__ ssq) {
    const int b = blockIdx.x;
    const int t = threadIdx.x;
    const int m = t & 127, g = t >> 7;   // g: 0..3 (n-quarter)
    __shared__ float xs[128];
    __shared__ float part[4][128];
    if (t < 128) xs[t] = xest[b * 128 + t];
    __syncthreads();
    const float* BBb = BBsum + (size_t)b * 16384;
    float s = 0.f;
#pragma unroll 8
    for (int n = g * 32; n < g * 32 + 32; ++n)
        s = fmaf(xs[n], BBb[n * 128 + m], s);
    part[g][m] = s;
    __syncthreads();
    if (t < 128) {
        float aux = part[0][m] + part[1][m] + part[2][m] + part[3][m] - Bz[b * 128 + m];
        float xe = xs[m];
        float out = fmaf(aux, w1[l * 128 + m], b1[l * 128 + m]) +
                    fmaf(xe, w2[l * 128 + m], b2[l * 128 + m]);
        outbuf[b * 128 + m] = out;
        atomicAdd(&ssum[l * 128 + m], out);
        atomicAdd(&ssq[l * 128 + m], out * out);
    }
}

// ---------------- layer B: BN + mask + clip(2v) + loss terms ----------------
__global__ __launch_bounds__(512) void layerB(const float* __restrict__ outbuf,
                                              const float* __restrict__ ssum,
                                              const float* __restrict__ ssq,
                                              const float* __restrict__ gamma,
                                              const float* __restrict__ beta,
                                              const float* __restrict__ Mask,
                                              int l,
                                              const float* __restrict__ G,
                                              const float* __restrict__ c,
                                              float* __restrict__ xest,
                                              float* __restrict__ dout,
                                              float* __restrict__ quad,
                                              float* __restrict__ lin) {
    const int b = blockIdx.x;
    const int t = threadIdx.x;
    const int m = t & 127, g = t >> 7;
    __shared__ float xs[128];
    __shared__ float part[4][128];
    __shared__ float red[16];
    if (t < 128) {
        float mu = ssum[l * 128 + t] * (1.0f / 256.0f);
        float var = ssq[l * 128 + t] * (1.0f / 256.0f) - mu * mu;
        float inv = 1.0f / sqrtf(var + 1e-5f);
        float v = (outbuf[b * 128 + t] - mu) * inv * gamma[l * 128 + t] + beta[l * 128 + t];
        v *= Mask[b * 128 + t];
        // _piecewise_clip(v) == clamp(2v, -1, 1)
        float xe = fminf(1.0f, fmaxf(-1.0f, 2.0f * v));
        xs[t] = xe;
        xest[b * 128 + t] = xe;
        dout[b * 128 + t] = xe;   // x_est output region (last layer's value survives)
    }
    __syncthreads();
    const float* Gb = G + (size_t)b * 16384;
    float s = 0.f;
#pragma unroll 8
    for (int n = g * 32; n < g * 32 + 32; ++n)
        s = fmaf(xs[n], Gb[n * 128 + m], s);
    part[g][m] = s;
    __syncthreads();
    float vq = 0.f, vl = 0.f;
    if (t < 128) {
        float sm = part[0][m] + part[1][m] + part[2][m] + part[3][m];
        vq = xs[m] * sm;            // contributes to x^T G x
        vl = xs[m] * c[b * 128 + m];// contributes to x . c
    }
#pragma unroll
    for (int off = 32; off; off >>= 1) {
        vq += __shfl_down(vq, off);
        vl += __shfl_down(vl, off);
    }
    const int wid = t >> 6, lane = t & 63;
    if (lane == 0) { red[wid] = vq; red[8 + wid] = vl; }
    __syncthreads();
    if (t == 0) {
        float q = 0.f, L = 0.f;
#pragma unroll
        for (int w = 0; w < 8; ++w) { q += red[w]; L += red[8 + w]; }
        atomicAdd(&quad[l], q);
        atomicAdd(&lin[l], L);
    }
}

// ---------------- final: losses[l] = log(l+1) * (Z2 - 2 lin + quad)/32768 ----------------
__global__ void final_losses(const float* __restrict__ quad,
                             const float* __restrict__ lin,
                             const float* __restrict__ Z2,
                             float* __restrict__ dout) {
    int l = threadIdx.x;
    if (l < 8) {
        const float logs[8] = {0.0f,
                               0.6931471805599453f,
                               1.0986122886681098f,
                               1.3862943611198906f,
                               1.6094379124341003f,
                               1.7917594692280550f,
                               1.9459101490553132f,
                               2.0794415416798357f};
        float dis = (Z2[0] - 2.0f * lin[l] + quad[l]) * (1.0f / 32768.0f);
        dout[32768 + l] = logs[l] * dis;
    }
}

extern "C" void kernel_launch(void* const* d_in, const int* in_sizes, int n_in,
                              void* d_out, int out_size, void* d_ws, size_t ws_size,
                              hipStream_t stream) {
    (void)in_sizes; (void)n_in; (void)out_size; (void)ws_size;
    const float* BB    = (const float*)d_in[0];
    const float* zB    = (const float*)d_in[1];
    // d_in[2] = x : unused (x_est starts at zeros)
    const float* z     = (const float*)d_in[3];
    const float* Bmat  = (const float*)d_in[4];
    const float* Mask  = (const float*)d_in[5];
    const float* w1    = (const float*)d_in[6];
    const float* b1    = (const float*)d_in[7];
    const float* w2    = (const float*)d_in[8];
    const float* b2    = (const float*)d_in[9];
    const float* gamma = (const float*)d_in[10];
    const float* beta  = (const float*)d_in[11];

    float* ws  = (float*)d_ws;
    float* out = (float*)d_out;

    float* BBsum = ws + OFF_BBSUM;
    float* G     = ws + OFF_G;
    float* c     = ws + OFF_C;
    float* Bz    = ws + OFF_BZ;
    float* outb  = ws + OFF_OUT;
    float* xe    = ws + OFF_XE;
    float* ssum  = ws + OFF_SSUM;
    float* ssq   = ws + OFF_SSQ;
    float* quad  = ws + OFF_QUAD;
    float* lin   = ws + OFF_LIN;
    float* Z2    = ws + OFF_Z2;

    zero_kernel<<<(int)((ZERO_COUNT + 255) / 256), 256, 0, stream>>>(ws + ZERO_START, (int)ZERO_COUNT);
    reduce_bb<<<16384, 256, 0, stream>>>(BB, BBsum);
    reduce_zb<<<128, 256, 0, stream>>>(zB, Bz);
    z2_kernel<<<1024, 256, 0, stream>>>(z, Z2);
    gram_mfma<<<256, 1024, 0, stream>>>(Bmat, z, G, c);
    for (int l = 0; l < NL; ++l) {
        layerA<<<256, 512, 0, stream>>>(xe, BBsum, Bz, w1, b1, w2, b2, l, outb, ssum, ssq);
        layerB<<<256, 512, 0, stream>>>(outb, ssum, ssq, gamma, beta, Mask, l, G, c, xe, out, quad, lin);
    }
    final_losses<<<1, 64, 0, stream>>>(quad, lin, Z2, out);
}